// Round 1
// 213.646 us; speedup vs baseline: 1.0055x; 1.0055x over previous
//
#include <hip/hip_runtime.h>
#include <hip/hip_bf16.h>

// Problem constants
#define B_ 8
#define T_ 1024
#define E_ 768
#define H_ 12
#define DH_ 64
#define E3_ 2304
#define M_ (B_ * T_)           // 8192 rows
// SCALE * log2(e): p = exp2(s * 0.125 * 1.4426950408889634)
// Applied to Q in gemm1's epilogue, NOT in the attention kernel.
#define SCALE_LOG2E 0.18033688011112042f

typedef __attribute__((ext_vector_type(8))) short short8;
typedef __attribute__((ext_vector_type(4))) float float4_;
typedef __attribute__((ext_vector_type(4))) unsigned short ushort4_;

__device__ __forceinline__ unsigned short f2bf(float f) {
    union { float f; unsigned int u; } v; v.f = f;
    unsigned int r = v.u + 0x7fffu + ((v.u >> 16) & 1u);
    return (unsigned short)(r >> 16);
}

// async global->LDS, 16B per lane. LDS dest must be wave-uniform base + lane*16.
__device__ __forceinline__ void gld_lds16(const unsigned short* g, unsigned short* l) {
    __builtin_amdgcn_global_load_lds(
        (const __attribute__((address_space(1))) void*)g,
        (__attribute__((address_space(3))) void*)l,
        16, 0, 0);
}

// ---------------------------------------------------------------------------
// prep: one kernel for all prepasses (unchanged).
// ---------------------------------------------------------------------------
__global__ __launch_bounds__(256) void prep(const float* __restrict__ hs,
                                            const float* __restrict__ qkv_w,
                                            const float* __restrict__ proj_w,
                                            unsigned short* __restrict__ hs_bf,
                                            unsigned short* __restrict__ qkvwT,
                                            unsigned short* __restrict__ projwT) {
    __shared__ float tile[32][33];
    const int id = blockIdx.x;
    const int tid = threadIdx.x;
    if (id < 6144) {
        const int i = (id * 256 + tid) * 4;
        float4_ v = *(const float4_*)(hs + i);
        ushort4_ o;
        o.x = f2bf(v.x); o.y = f2bf(v.y); o.z = f2bf(v.z); o.w = f2bf(v.w);
        *(ushort4_*)(hs_bf + i) = o;
        return;
    }
    const float* W; unsigned short* Wt; int N, bx, by;
    if (id < 6144 + 1728) {
        const int t = id - 6144; W = qkv_w; Wt = qkvwT; N = E3_;
        bx = t % 72; by = t / 72;
    } else {
        const int t = id - 7872; W = proj_w; Wt = projwT; N = E_;
        bx = t % 24; by = t / 24;
    }
    const int k0 = by * 32, n0 = bx * 32;
    const int tx = tid & 31, ty = tid >> 5;
    for (int i = ty; i < 32; i += 8)
        tile[i][tx] = W[(size_t)(k0 + i) * N + n0 + tx];
    __syncthreads();
    for (int i = ty; i < 32; i += 8)
        Wt[(size_t)(n0 + i) * E_ + k0 + tx] = f2bf(tile[tx][i]);
}

// ---------------------------------------------------------------------------
// OLD 128x128 2-phase GEMM: kept for the output projection (N=768 would
// underfill the 256^2 grid: only 96 blocks).
// ---------------------------------------------------------------------------
template <int STORE_MODE>
__global__ __launch_bounds__(256) void gemm_mfma(const unsigned short* __restrict__ A,
                                                 const unsigned short* __restrict__ Wt,
                                                 const float* __restrict__ bias,
                                                 void* __restrict__ Cout,
                                                 unsigned short* __restrict__ Vt,
                                                 int M, int N, int K) {
    __shared__ __align__(16) unsigned short Al[2][128 * 32];
    __shared__ __align__(16) unsigned short Wl[2][128 * 32];

    const int tid = threadIdx.x;
    const int lane = tid & 63;
    const int w = tid >> 6;

    const int id = blockIdx.x;
    const int xcd = id & 7;
    const int slot = id >> 3;
    const int bx = slot >> 3;
    const int by = xcd * 8 + (slot & 7);
    const int bm = by * 128;
    const int bn = bx * 128;

    const int wm = (w >> 1) * 64;
    const int wn = (w & 1) * 64;
    const int quad = lane >> 4;
    const int l16 = lane & 15;

    const int srow = w * 32 + (lane >> 2);
    const int schunk = (lane & 3) * 8;
    const int sbase = w * 32 * 32 + lane * 8;

    const unsigned short* ga = A + (size_t)(bm + srow) * K + schunk;
    const unsigned short* gw = Wt + (size_t)(bn + srow) * K + schunk;

    float4_ acc[4][4] = {};

    gld_lds16(ga, &Al[0][sbase]);
    gld_lds16(ga + (size_t)16 * K, &Al[0][sbase + 512]);
    gld_lds16(gw, &Wl[0][sbase]);
    gld_lds16(gw + (size_t)16 * K, &Wl[0][sbase + 512]);

    const int NI = K >> 5;
    for (int i = 0; i < NI; ++i) {
        const int cur = i & 1;
        __syncthreads();
        if (i + 1 < NI) {
            const unsigned short* ga2 = ga + (size_t)(i + 1) * 32;
            const unsigned short* gw2 = gw + (size_t)(i + 1) * 32;
            const int nxt = cur ^ 1;
            gld_lds16(ga2, &Al[nxt][sbase]);
            gld_lds16(ga2 + (size_t)16 * K, &Al[nxt][sbase + 512]);
            gld_lds16(gw2, &Wl[nxt][sbase]);
            gld_lds16(gw2 + (size_t)16 * K, &Wl[nxt][sbase + 512]);
        }
        short8 af[4], bf[4];
#pragma unroll
        for (int mt = 0; mt < 4; ++mt)
            af[mt] = *(const short8*)(&Al[cur][(wm + mt * 16 + l16) * 32 + quad * 8]);
#pragma unroll
        for (int nt = 0; nt < 4; ++nt)
            bf[nt] = *(const short8*)(&Wl[cur][(wn + nt * 16 + l16) * 32 + quad * 8]);
#pragma unroll
        for (int mt = 0; mt < 4; ++mt)
#pragma unroll
            for (int nt = 0; nt < 4; ++nt)
                acc[mt][nt] = __builtin_amdgcn_mfma_f32_16x16x32_bf16(af[mt], bf[nt],
                                                                      acc[mt][nt], 0, 0, 0);
    }

    {
        const float qs = 1.0f;
#pragma unroll
        for (int nt = 0; nt < 4; ++nt) {
            const int col = bn + wn + nt * 16 + l16;
            const float bv = bias[col];
#pragma unroll
            for (int mt = 0; mt < 4; ++mt) {
#pragma unroll
                for (int i = 0; i < 4; ++i) {
                    const int row = bm + wm + mt * 16 + quad * 4 + i;
                    const float v = (acc[mt][nt][i] + bv) * qs;
                    if (STORE_MODE >= 1)
                        ((unsigned short*)Cout)[(size_t)row * N + col] = f2bf(v);
                    else
                        ((float*)Cout)[(size_t)row * N + col] = v;
                }
            }
        }
    }
    (void)Vt;
}

// ---------------------------------------------------------------------------
// NEW: 256x256 8-phase GEMM for the QKV projection (M=8192, N=2304, K=768).
// 512 threads = 8 waves (2 M-halves x 4 N-slices of 64 cols), BK=64.
// LDS ring = 2 K-tiles x {A,B} x {2 halves} = 128 KiB. Each half-tile is
// staged as 2 "sweeps" of one gld_lds each (8 KB = 512 lanes x 16B):
//   A half: sweep s = rows s*64..s*64+63 (row-major [row][64k])
//   B half: stored at permuted col index c^ = swap(bit5,bit6)(col) so that
//           sweep s == all cols read by MFMA col-group nh=s (contiguous in c^)
// Chunk swizzle (T2): 16B-chunk ^= (ldsrow&7), applied on the GLOBAL source
// address (LDS dest stays linear for gld_lds) and on the ds_read address.
// Schedule (T3+T4): phases (mh,nh) per K-tile, 8/iter over 2 K-tiles; one
// sweep-pair staged per phase with >=5-phase issue->consume lag; uniform
// s_waitcnt vmcnt(8) per phase end (8 loads always in flight; never 0 in
// steady state). Stagger (stage phase -> first-read phase, lag >=6):
//   P1: buf1 A.s1(t1)->P7 | P2: buf0 A.s0(t2)->nextP1 | P3: buf0 B.s0->nextP1
//   P4: buf0 B.s1->nextP2 | P5: buf0 A.s1->nextP3     | P6: buf1 A.s0(t3)->nextP5
//   P7: buf1 B.s0->nextP5 | P8: buf1 B.s1->nextP6
// Tail: last iter P4 waits vmcnt(0) (stages P2..P8 are predicated off, so
// the steady-state ring guard no longer covers P5..P7's reads).
// ---------------------------------------------------------------------------
template <int STORE_MODE>
__global__ __launch_bounds__(512, 2) void gemm256(const unsigned short* __restrict__ A,
                                                  const unsigned short* __restrict__ Wt,
                                                  const float* __restrict__ bias,
                                                  void* __restrict__ Cout,
                                                  unsigned short* __restrict__ Vt,
                                                  int M, int N, int K) {
    __shared__ __align__(16) unsigned short lds[65536];   // 128 KiB

    const int tid = threadIdx.x;
    const int lane = tid & 63;
    const int w = tid >> 6;          // 0..7
    const int quad = lane >> 4;
    const int l16 = lane & 15;

    // grid 288 = 8 xcd * (9 bx * 4 byl), byl innermost (B-panel L2 reuse)
    const int id = blockIdx.x;
    const int xcd = id & 7;
    const int slot = id >> 3;        // 0..35
    const int bx = slot >> 2;        // 0..8
    const int byl = slot & 3;        // 0..3
    const int bm = (xcd * 4 + byl) * 256;
    const int bn = bx * 256;

    // ---- staging constants (per thread) ----
    const int rb = tid >> 3;                                  // lds row within sweep
    const int csw = (((tid & 7) ^ (rb & 7)) << 3);            // swizzled src chunk (elems)
    const unsigned short* ga = A + (size_t)(bm + rb) * K + csw;
    const unsigned short* gb = Wt + (size_t)(bn + (rb & 31) + ((rb >> 5) & 1) * 64) * K + csw;
    unsigned short* ldst = lds + tid * 8;

    // stage macros: p=ring slot, h=region half, s=sweep, kt=K-tile index
#define STA(p, h, s, kt) gld_lds16(ga + ((size_t)((h) * 128 + (s) * 64) * K + (kt) * 64), \
                                   ldst + ((p) * 2 + (h)) * 8192 + (s) * 4096)
#define STB(p, h, s, kt) gld_lds16(gb + ((size_t)((h) * 128 + (s) * 32) * K + (kt) * 64), \
                                   ldst + 32768 + ((p) * 2 + (h)) * 8192 + (s) * 4096)

    // ---- fragment-read constants ----
    const int sw0 = ((quad ^ (l16 & 7)) << 3);                // k-chunk 0..3 (ks=0)
    const int sw1 = (((quad + 4) ^ (l16 & 7)) << 3);          // k-chunk 4..7 (ks=1)
    const unsigned short* rdA = lds + (w >> 2) * 8192 + l16 * 64;
    const unsigned short* rdB = lds + 32768 + ((w & 3) >> 1) * 8192 + ((w & 1) * 32 + l16) * 64;

    short8 aF[4][2], bF0[2][2], bF1[2][2];
    float4_ acc[8][4] = {};

#define LDA(p, mh) { \
    const unsigned short* _a = rdA + (p) * 16384 + (mh) * 4096; \
    _Pragma("unroll") for (int mt = 0; mt < 4; ++mt) { \
        aF[mt][0] = *(const short8*)(_a + mt * 1024 + sw0); \
        aF[mt][1] = *(const short8*)(_a + mt * 1024 + sw1); } }
#define LDB(dst, p, nh) { \
    const unsigned short* _b = rdB + (p) * 16384 + (nh) * 4096; \
    dst[0][0] = *(const short8*)(_b + sw0); \
    dst[0][1] = *(const short8*)(_b + sw1); \
    dst[1][0] = *(const short8*)(_b + 1024 + sw0); \
    dst[1][1] = *(const short8*)(_b + 1024 + sw1); }

#define MMA(mh, nh, BF) \
    __builtin_amdgcn_s_barrier(); \
    asm volatile("s_waitcnt lgkmcnt(0)" ::: "memory"); \
    __builtin_amdgcn_sched_barrier(0); \
    __builtin_amdgcn_s_setprio(1); \
    _Pragma("unroll") for (int mt = 0; mt < 4; ++mt) \
    _Pragma("unroll") for (int nt = 0; nt < 2; ++nt) { \
        acc[(mh) * 4 + mt][(nh) * 2 + nt] = __builtin_amdgcn_mfma_f32_16x16x32_bf16( \
            aF[mt][0], BF[nt][0], acc[(mh) * 4 + mt][(nh) * 2 + nt], 0, 0, 0); \
        acc[(mh) * 4 + mt][(nh) * 2 + nt] = __builtin_amdgcn_mfma_f32_16x16x32_bf16( \
            aF[mt][1], BF[nt][1], acc[(mh) * 4 + mt][(nh) * 2 + nt], 0, 0, 0); } \
    __builtin_amdgcn_s_setprio(0);

#define WAITV8 asm volatile("s_waitcnt vmcnt(8)" ::: "memory"); __builtin_amdgcn_s_barrier();

    // ---- prologue: tile0 complete (8 loads) + tile1 {A.s0, B.s0, B.s1} (6) ----
    STA(0, 0, 0, 0); STA(0, 1, 0, 0);
    STB(0, 0, 0, 0); STB(0, 1, 0, 0);
    STB(0, 0, 1, 0); STB(0, 1, 1, 0);
    STA(0, 0, 1, 0); STA(0, 1, 1, 0);
    STA(1, 0, 0, 1); STA(1, 1, 0, 1);
    STB(1, 0, 0, 1); STB(1, 1, 0, 1);
    STB(1, 0, 1, 1); STB(1, 1, 1, 1);
    asm volatile("s_waitcnt vmcnt(6)" ::: "memory");
    __builtin_amdgcn_s_barrier();

    const int NJ = K >> 7;   // 2 K-tiles (BK=64) per iteration; K=768 -> 6
#pragma unroll 1
    for (int j = 0; j < NJ; ++j) {
        const int t1 = 2 * j + 1, t2 = 2 * j + 2, t3 = 2 * j + 3;
        const bool st = (j < NJ - 1);

        // P1 (buf0, mh0, nh0)
        LDA(0, 0); LDB(bF0, 0, 0);
        STA(1, 0, 1, t1); STA(1, 1, 1, t1);
        MMA(0, 0, bF0);
        WAITV8;
        // P2 (buf0, mh0, nh1)
        LDB(bF1, 0, 1);
        if (st) { STA(0, 0, 0, t2); STA(0, 1, 0, t2); }
        MMA(0, 1, bF1);
        WAITV8;
        // P3 (buf0, mh1, nh0)
        LDA(0, 1);
        if (st) { STB(0, 0, 0, t2); STB(0, 1, 0, t2); }
        MMA(1, 0, bF0);
        WAITV8;
        // P4 (buf0, mh1, nh1)  [tail: full drain closes the ring guard]
        if (st) { STB(0, 0, 1, t2); STB(0, 1, 1, t2); }
        MMA(1, 1, bF1);
        if (j == NJ - 1) asm volatile("s_waitcnt vmcnt(0)" ::: "memory");
        else             asm volatile("s_waitcnt vmcnt(8)" ::: "memory");
        __builtin_amdgcn_s_barrier();
        // P5 (buf1, mh0, nh0)
        LDA(1, 0); LDB(bF0, 1, 0);
        if (st) { STA(0, 0, 1, t2); STA(0, 1, 1, t2); }
        MMA(0, 0, bF0);
        WAITV8;
        // P6 (buf1, mh0, nh1)
        LDB(bF1, 1, 1);
        if (st) { STA(1, 0, 0, t3); STA(1, 1, 0, t3); }
        MMA(0, 1, bF1);
        WAITV8;
        // P7 (buf1, mh1, nh0)
        LDA(1, 1);
        if (st) { STB(1, 0, 0, t3); STB(1, 1, 0, t3); }
        MMA(1, 0, bF0);
        WAITV8;
        // P8 (buf1, mh1, nh1)
        if (st) { STB(1, 0, 1, t3); STB(1, 1, 1, t3); }
        MMA(1, 1, bF1);
        WAITV8;
    }
#undef STA
#undef STB
#undef LDA
#undef LDB
#undef MMA
#undef WAITV8

    // ---- epilogue: rows = bm + (w>>2)*128 + (mi>>2)*64 + (mi&3)*16 + quad*4 + i
    //                cols = bn + (w&3)*64 + (ni>>1)*32 + (ni&1)*16 + l16
    if (STORE_MODE == 2 && bn >= 1536) {
        const int b = bm >> 10;
        const int tloc = (bm & 1023) + (w >> 2) * 128;
#pragma unroll
        for (int ni = 0; ni < 4; ++ni) {
            const int col = bn + (w & 3) * 64 + (ni >> 1) * 32 + (ni & 1) * 16 + l16;
            const int n = col - 1536;
            const int h = n >> 6, d = n & 63;
            const float bv = bias[col];
            const size_t vrow = (size_t)((b * H_ + h) * 64 + d) * T_;
#pragma unroll
            for (int mi = 0; mi < 8; ++mi) {
                ushort4_ pk;
                pk.x = f2bf(acc[mi][ni][0] + bv);
                pk.y = f2bf(acc[mi][ni][1] + bv);
                pk.z = f2bf(acc[mi][ni][2] + bv);
                pk.w = f2bf(acc[mi][ni][3] + bv);
                *(ushort4_*)(Vt + vrow + tloc + (mi >> 2) * 64 + (mi & 3) * 16 + quad * 4) = pk;
            }
        }
    } else {
        const float qs = (STORE_MODE == 2 && bn < 768) ? SCALE_LOG2E : 1.0f;
#pragma unroll
        for (int ni = 0; ni < 4; ++ni) {
            const int col = bn + (w & 3) * 64 + (ni >> 1) * 32 + (ni & 1) * 16 + l16;
            const float bv = bias[col];
#pragma unroll
            for (int mi = 0; mi < 8; ++mi) {
#pragma unroll
                for (int i = 0; i < 4; ++i) {
                    const int row = bm + (w >> 2) * 128 + (mi >> 2) * 64 + (mi & 3) * 16 + quad * 4 + i;
                    const float v = (acc[mi][ni][i] + bv) * qs;
                    if (STORE_MODE >= 1)
                        ((unsigned short*)Cout)[(size_t)row * N + col] = f2bf(v);
                    else
                        ((float*)Cout)[(size_t)row * N + col] = v;
                }
            }
        }
    }
}

// ---------------------------------------------------------------------------
// MFMA flash attention (unchanged this round).
// ---------------------------------------------------------------------------
__global__ __launch_bounds__(256) void attn_mfma(const unsigned short* __restrict__ mixed,
                                                 const unsigned short* __restrict__ Vt,
                                                 unsigned short* __restrict__ ctx) {
    const int bh = blockIdx.x;
    const int b = bh / H_;
    const int h = bh % H_;
    const int q0 = blockIdx.y * 128;
    const int tid = threadIdx.x;
    const int lane = tid & 63;
    const int w = tid >> 6;
    const int quad = lane >> 4;
    const int l16 = lane & 15;

    __shared__ __align__(16) unsigned short Kl[8 * 520];
    __shared__ __align__(16) unsigned short Vl[8 * 520];
    __shared__ __align__(16) unsigned short Pl[4][32 * 72];
    unsigned short* pw = &Pl[w][0];

    short8 qf[2][2];
#pragma unroll
    for (int hh = 0; hh < 2; ++hh) {
        const size_t qrow = (size_t)(b * T_ + q0 + w * 32 + hh * 16 + l16) * E3_ + h * 64;
        qf[hh][0] = *(const short8*)(mixed + qrow + quad * 8);
        qf[hh][1] = *(const short8*)(mixed + qrow + 32 + quad * 8);
    }

    float4_ o[2][4] = {};
    float lps[2] = {0.0f, 0.0f};

    const size_t kbase = (size_t)(b * T_) * E3_ + E_ + h * 64;
    const size_t vtb = (size_t)bh * 64 * T_;

    const int srow = tid >> 3;
    const int sc = tid & 7;

    for (int kv0 = 0; kv0 < T_; kv0 += 64) {
        short8 k1 = *(const short8*)(mixed + kbase + (size_t)(kv0 + srow) * E3_ + sc * 8);
        short8 k2 = *(const short8*)(mixed + kbase + (size_t)(kv0 + srow + 32) * E3_ + sc * 8);
        short8 v1 = *(const short8*)(Vt + vtb + (size_t)srow * T_ + kv0 + sc * 8);
        short8 v2 = *(const short8*)(Vt + vtb + (size_t)(srow + 32) * T_ + kv0 + sc * 8);
        __syncthreads();
        *(short8*)(&Kl[sc * 520 + srow * 8]) = k1;
        *(short8*)(&Kl[sc * 520 + (srow + 32) * 8]) = k2;
        *(short8*)(&Vl[sc * 520 + srow * 8]) = v1;
        *(short8*)(&Vl[sc * 520 + (srow + 32) * 8]) = v2;
        __syncthreads();

        float4_ st[2][4];
#pragma unroll
        for (int nt = 0; nt < 4; ++nt) {
            const int key = nt * 16 + l16;
            short8 kf0 = *(const short8*)(&Kl[quad * 520 + key * 8]);
            short8 kf1 = *(const short8*)(&Kl[(4 + quad) * 520 + key * 8]);
#pragma unroll
            for (int hh = 0; hh < 2; ++hh) {
                float4_ z = {};
                z = __builtin_amdgcn_mfma_f32_16x16x32_bf16(kf0, qf[hh][0], z, 0, 0, 0);
                st[hh][nt] = __builtin_amdgcn_mfma_f32_16x16x32_bf16(kf1, qf[hh][1], z, 0, 0, 0);
            }
        }

#pragma unroll
        for (int hh = 0; hh < 2; ++hh) {
#pragma unroll
            for (int nt = 0; nt < 4; ++nt) {
                ushort4_ pk;
                float p0 = exp2f(st[hh][nt][0]);
                float p1 = exp2f(st[hh][nt][1]);
                float p2 = exp2f(st[hh][nt][2]);
                float p3 = exp2f(st[hh][nt][3]);
                pk.x = f2bf(p0); pk.y = f2bf(p1); pk.z = f2bf(p2); pk.w = f2bf(p3);
                lps[hh] += (p0 + p1) + (p2 + p3);
                *(ushort4_*)(&pw[(hh * 16 + l16) * 72 + nt * 16 + quad * 4]) = pk;
            }
        }

        short8 pf[2][2];
#pragma unroll
        for (int hh = 0; hh < 2; ++hh) {
            pf[hh][0] = *(const short8*)(&pw[(hh * 16 + l16) * 72 + quad * 8]);
            pf[hh][1] = *(const short8*)(&pw[(hh * 16 + l16) * 72 + 32 + quad * 8]);
        }

#pragma unroll
        for (int dt = 0; dt < 4; ++dt) {
            const int d = dt * 16 + l16;
            short8 vf0 = *(const short8*)(&Vl[quad * 520 + d * 8]);
            short8 vf1 = *(const short8*)(&Vl[(4 + quad) * 520 + d * 8]);
#pragma unroll
            for (int hh = 0; hh < 2; ++hh) {
                o[hh][dt] = __builtin_amdgcn_mfma_f32_16x16x32_bf16(pf[hh][0], vf0, o[hh][dt], 0, 0, 0);
                o[hh][dt] = __builtin_amdgcn_mfma_f32_16x16x32_bf16(pf[hh][1], vf1, o[hh][dt], 0, 0, 0);
            }
        }
    }

#pragma unroll
    for (int hh = 0; hh < 2; ++hh) {
        float l = lps[hh];
        l += __shfl_xor(l, 16, 64);
        l += __shfl_xor(l, 32, 64);
        float4_ inv;
#pragma unroll
        for (int i = 0; i < 4; ++i)
            inv[i] = 1.0f / __shfl(l, quad * 4 + i, 16);
#pragma unroll
        for (int dt = 0; dt < 4; ++dt) {
#pragma unroll
            for (int i = 0; i < 4; ++i) {
                const float v = o[hh][dt][i] * inv[i];
                const size_t row = (size_t)(b * T_ + q0 + w * 32 + hh * 16 + quad * 4 + i);
                ctx[row * E_ + h * 64 + dt * 16 + l16] = f2bf(v);
            }
        }
    }
}

// ---------------------------------------------------------------------------
extern "C" void kernel_launch(void* const* d_in, const int* in_sizes, int n_in,
                              void* d_out, int out_size, void* d_ws, size_t ws_size,
                              hipStream_t stream) {
    const float* hs     = (const float*)d_in[0];
    const float* qkv_w  = (const float*)d_in[1];
    const float* qkv_b  = (const float*)d_in[2];
    const float* proj_w = (const float*)d_in[3];
    const float* proj_b = (const float*)d_in[4];
    float* out = (float*)d_out;

    unsigned short* hs_bf  = (unsigned short*)d_ws;                 // [8192][768]
    unsigned short* qkvwT  = hs_bf + (size_t)M_ * E_;               // [2304][768]
    unsigned short* projwT = qkvwT + (size_t)E3_ * E_;              // [768][768]
    unsigned short* mixed  = projwT + (size_t)E_ * E_;              // [8192][2304]
    unsigned short* Vt     = mixed + (size_t)M_ * E3_;              // [96*64][1024]
    unsigned short* ctx    = hs_bf;  // alias: hs_bf dead after GEMM1

    // 0) fused prepasses: cast + both weight transposes
    prep<<<8448, 256, 0, stream>>>(hs, qkv_w, proj_w, hs_bf, qkvwT, projwT);

    // 1) QKV projection -> mixed (Q scaled, K bf16) + Vt (V transposed)
    //    NEW: 256x256 8-phase counted-vmcnt schedule, 288 blocks x 512 thr
    gemm256<2><<<(E3_ / 256) * (M_ / 256), 512, 0, stream>>>(hs_bf, qkvwT, qkv_b,
                                                             (void*)mixed, Vt, M_, E3_, E_);
    // 2) attention -> ctx (bf16)
    attn_mfma<<<dim3(B_ * H_, T_ / 128), 256, 0, stream>>>(mixed, Vt, ctx);
    // 3) output projection -> out (fp32), old 128x128 structure
    gemm_mfma<0><<<(E_ / 128) * (M_ / 128), 256, 0, stream>>>(ctx, projwT, proj_b,
                                                              (void*)out, nullptr, M_, E_, E_);
}

// Round 2
// 191.811 us; speedup vs baseline: 1.1199x; 1.1138x over previous
//
#include <hip/hip_runtime.h>
#include <hip/hip_bf16.h>

// Problem constants
#define B_ 8
#define T_ 1024
#define E_ 768
#define H_ 12
#define DH_ 64
#define E3_ 2304
#define M_ (B_ * T_)           // 8192 rows
// SCALE * log2(e): p = exp2(s * 0.125 * 1.4426950408889634)
// Applied to Q in gemm288's epilogue, NOT in the attention kernel.
#define SCALE_LOG2E 0.18033688011112042f

typedef __attribute__((ext_vector_type(8))) short short8;
typedef __attribute__((ext_vector_type(4))) float float4_;
typedef __attribute__((ext_vector_type(4))) unsigned short ushort4_;

__device__ __forceinline__ unsigned short f2bf(float f) {
    union { float f; unsigned int u; } v; v.f = f;
    unsigned int r = v.u + 0x7fffu + ((v.u >> 16) & 1u);
    return (unsigned short)(r >> 16);
}

// async global->LDS, 16B per lane. LDS dest must be wave-uniform base + lane*16.
__device__ __forceinline__ void gld_lds16(const unsigned short* g, unsigned short* l) {
    __builtin_amdgcn_global_load_lds(
        (const __attribute__((address_space(1))) void*)g,
        (__attribute__((address_space(3))) void*)l,
        16, 0, 0);
}

// ---------------------------------------------------------------------------
// prep: one kernel for all prepasses (unchanged).
// ---------------------------------------------------------------------------
__global__ __launch_bounds__(256) void prep(const float* __restrict__ hs,
                                            const float* __restrict__ qkv_w,
                                            const float* __restrict__ proj_w,
                                            unsigned short* __restrict__ hs_bf,
                                            unsigned short* __restrict__ qkvwT,
                                            unsigned short* __restrict__ projwT) {
    __shared__ float tile[32][33];
    const int id = blockIdx.x;
    const int tid = threadIdx.x;
    if (id < 6144) {
        const int i = (id * 256 + tid) * 4;
        float4_ v = *(const float4_*)(hs + i);
        ushort4_ o;
        o.x = f2bf(v.x); o.y = f2bf(v.y); o.z = f2bf(v.z); o.w = f2bf(v.w);
        *(ushort4_*)(hs_bf + i) = o;
        return;
    }
    const float* W; unsigned short* Wt; int N, bx, by;
    if (id < 6144 + 1728) {
        const int t = id - 6144; W = qkv_w; Wt = qkvwT; N = E3_;
        bx = t % 72; by = t / 72;
    } else {
        const int t = id - 7872; W = proj_w; Wt = projwT; N = E_;
        bx = t % 24; by = t / 24;
    }
    const int k0 = by * 32, n0 = bx * 32;
    const int tx = tid & 31, ty = tid >> 5;
    for (int i = ty; i < 32; i += 8)
        tile[i][tx] = W[(size_t)(k0 + i) * N + n0 + tx];
    __syncthreads();
    for (int i = ty; i < 32; i += 8)
        Wt[(size_t)(n0 + i) * E_ + k0 + tx] = f2bf(tile[tx][i]);
}

// ---------------------------------------------------------------------------
// OLD 128x128 2-phase GEMM: kept for the output projection (N=768; 384 blocks
// at 2 blocks/CU co-resident).
// ---------------------------------------------------------------------------
template <int STORE_MODE>
__global__ __launch_bounds__(256) void gemm_mfma(const unsigned short* __restrict__ A,
                                                 const unsigned short* __restrict__ Wt,
                                                 const float* __restrict__ bias,
                                                 void* __restrict__ Cout,
                                                 unsigned short* __restrict__ Vt,
                                                 int M, int N, int K) {
    __shared__ __align__(16) unsigned short Al[2][128 * 32];
    __shared__ __align__(16) unsigned short Wl[2][128 * 32];

    const int tid = threadIdx.x;
    const int lane = tid & 63;
    const int w = tid >> 6;

    const int id = blockIdx.x;
    const int xcd = id & 7;
    const int slot = id >> 3;
    const int bx = slot >> 3;
    const int by = xcd * 8 + (slot & 7);
    const int bm = by * 128;
    const int bn = bx * 128;

    const int wm = (w >> 1) * 64;
    const int wn = (w & 1) * 64;
    const int quad = lane >> 4;
    const int l16 = lane & 15;

    const int srow = w * 32 + (lane >> 2);
    const int schunk = (lane & 3) * 8;
    const int sbase = w * 32 * 32 + lane * 8;

    const unsigned short* ga = A + (size_t)(bm + srow) * K + schunk;
    const unsigned short* gw = Wt + (size_t)(bn + srow) * K + schunk;

    float4_ acc[4][4] = {};

    gld_lds16(ga, &Al[0][sbase]);
    gld_lds16(ga + (size_t)16 * K, &Al[0][sbase + 512]);
    gld_lds16(gw, &Wl[0][sbase]);
    gld_lds16(gw + (size_t)16 * K, &Wl[0][sbase + 512]);

    const int NI = K >> 5;
    for (int i = 0; i < NI; ++i) {
        const int cur = i & 1;
        __syncthreads();
        if (i + 1 < NI) {
            const unsigned short* ga2 = ga + (size_t)(i + 1) * 32;
            const unsigned short* gw2 = gw + (size_t)(i + 1) * 32;
            const int nxt = cur ^ 1;
            gld_lds16(ga2, &Al[nxt][sbase]);
            gld_lds16(ga2 + (size_t)16 * K, &Al[nxt][sbase + 512]);
            gld_lds16(gw2, &Wl[nxt][sbase]);
            gld_lds16(gw2 + (size_t)16 * K, &Wl[nxt][sbase + 512]);
        }
        short8 af[4], bf[4];
#pragma unroll
        for (int mt = 0; mt < 4; ++mt)
            af[mt] = *(const short8*)(&Al[cur][(wm + mt * 16 + l16) * 32 + quad * 8]);
#pragma unroll
        for (int nt = 0; nt < 4; ++nt)
            bf[nt] = *(const short8*)(&Wl[cur][(wn + nt * 16 + l16) * 32 + quad * 8]);
#pragma unroll
        for (int mt = 0; mt < 4; ++mt)
#pragma unroll
            for (int nt = 0; nt < 4; ++nt)
                acc[mt][nt] = __builtin_amdgcn_mfma_f32_16x16x32_bf16(af[mt], bf[nt],
                                                                      acc[mt][nt], 0, 0, 0);
    }

    {
#pragma unroll
        for (int nt = 0; nt < 4; ++nt) {
            const int col = bn + wn + nt * 16 + l16;
            const float bv = bias[col];
#pragma unroll
            for (int mt = 0; mt < 4; ++mt) {
#pragma unroll
                for (int i = 0; i < 4; ++i) {
                    const int row = bm + wm + mt * 16 + quad * 4 + i;
                    const float v = acc[mt][nt][i] + bv;
                    if (STORE_MODE >= 1)
                        ((unsigned short*)Cout)[(size_t)row * N + col] = f2bf(v);
                    else
                        ((float*)Cout)[(size_t)row * N + col] = v;
                }
            }
        }
    }
    (void)Vt;
}

// ---------------------------------------------------------------------------
// NEW: 256x288 3-phase GEMM for the QKV projection. Grid = (8192/256) x
// (2304/288) = 32 x 8 = 256 blocks = EXACTLY one block per CU -> single
// dispatch round (fixes the 288-block/2-round quantization that capped the
// previous 256x256 version at 62 us / MfmaUtil 17%).
//
// 512 threads = 8 waves as 4M x 2N; wave tile 64 x 144; acc[4][9] (144 AGPR).
// BK=64; LDS ring = 2 K-tiles x {A 32KB, B 36KB} + 1KB scratch = 137 KB.
// K-tile = 12 phases... : 3 phases per tile (nh thirds of 144 cols), each
// phase = 4mt x 3nt x 2ks = 24 MFMA. A frags loaded once per tile (phase 0).
//
// Staging: per-wave 1KB granules (gld_lds, 64 lanes x 16B). A tile = 32
// granules (4/wave: j = w+8m). B tile = 36 granules (4.5/wave: j = w+8m,
// waves 0-3 get a 5th, waves 4-7 pad with a dummy into LDS scratch so every
// wave issues EXACTLY 3 VMEM stages per phase -> uniform per-wave vmcnt).
// Tile t+1 is staged into the opposite buffer (its previous tile fully read
// one tile ago -> no mid-tile region hazards). Per-wave B granules are
// sorted by nh so nh0 granules land by phase 1.
//   phase0: stage A{w, w+8, w+16}   phase1: A{w+24}, B{b0,b1}   phase2: B{b2,b3,b4}
// Uniform s_waitcnt vmcnt(3) at every phase end: every granule read in the
// next phase is >=4 issues old in every wave's own stream (verified per
// case). Last tile peeled: no stages, vmcnt(0) to close the tail.
//
// Chunk swizzle (T2, measured 0-conflict in R1): 16B chunk ^= (row&7) on the
// GLOBAL source (LDS dest linear for gld_lds) and on the ds_read address.
//
// Epilogue: 288-col tiles straddle Q/K/V boundaries; branch per 16-col group
// (768/1536 are 16-aligned -> wave-uniform). Q scaled by SCALE_LOG2E, V
// written transposed to Vt.
// ---------------------------------------------------------------------------
__global__ __launch_bounds__(512, 2) void gemm288(const unsigned short* __restrict__ A,
                                                  const unsigned short* __restrict__ Wt,
                                                  const float* __restrict__ bias,
                                                  unsigned short* __restrict__ mixedOut,
                                                  unsigned short* __restrict__ Vt) {
    const int K = 768;
    const int NT = 12;                 // K / 64
    __shared__ __align__(16) unsigned short lds[70144]; // A:2*16384 | B:2*18432 | scratch:512

    const int tid = threadIdx.x;
    const int lane = tid & 63;
    const int w = tid >> 6;            // 0..7
    const int quad = lane >> 4;
    const int l16 = lane & 15;
    const int wM = w >> 1;             // 0..3 (64-row slice)
    const int wN = w & 1;              // 0..1 (144-col slice)

    // grid 256 = 8 xcd * (8 bx * 4 byl), byl innermost
    const int id = blockIdx.x;
    const int xcd = id & 7;
    const int slot = id >> 3;          // 0..31
    const int bx = slot >> 2;          // 0..7
    const int byl = slot & 3;
    const int bm = (xcd * 4 + byl) * 256;
    const int bn = bx * 288;

    // ---- B granule ownership, sorted by nh third (wave-uniform) ----
    // granule j covers cols j*8..j*8+7 ; nh(j) = (j%18)/6 ; dummy j=36 -> nh 3
    const int j4 = (w < 4) ? (w + 32) : 36;
    int kk0 = ((w % 18) / 6) * 64 + w;
    int kk1 = (((w + 8) % 18) / 6) * 64 + (w + 8);
    int kk2 = (((w + 16) % 18) / 6) * 64 + (w + 16);
    int kk3 = (((w + 24) % 18) / 6) * 64 + (w + 24);
    int kk4 = (j4 >= 36) ? (3 * 64 + 36) : (((j4 % 18) / 6) * 64 + j4);
#define CS_(a, b) { int _lo = min(a, b), _hi = max(a, b); a = _lo; b = _hi; }
    CS_(kk0, kk1) CS_(kk3, kk4) CS_(kk2, kk4) CS_(kk2, kk3) CS_(kk1, kk4)
    CS_(kk0, kk3) CS_(kk0, kk2) CS_(kk1, kk3) CS_(kk1, kk2)
#undef CS_
    const int b0 = kk0 & 63, b1 = kk1 & 63, b2 = kk2 & 63, b3 = kk3 & 63, b4 = kk4 & 63;

    // ---- staging constants ----
    const int srcrow = lane >> 3;                               // row within granule
    const int ssw = ((lane & 7) ^ (srcrow & 7)) << 3;           // swizzled src chunk (elems)
    const unsigned short* gaL = A + (size_t)(bm + srcrow) * K + ssw;
    const unsigned short* gbL = Wt + (size_t)(bn + srcrow) * K + ssw;
    unsigned short* ldsl = lds + lane * 8;

    // ---- fragment-read constants ----
    const int rsw0 = ((quad) ^ (l16 & 7)) << 3;                 // ks=0
    const int rsw1 = ((quad + 4) ^ (l16 & 7)) << 3;             // ks=1
    const unsigned short* rdA = lds + (wM * 64 + l16) * 64;
    const unsigned short* rdB = lds + 32768 + (wN * 144 + l16) * 64;

    short8 aF[4][2], bF[3][2];
    float4_ acc[4][9] = {};

#define STA_(aj, toff, bufA) gld_lds16(gaL + (size_t)(aj) * 6144 + (toff), (bufA) + (aj) * 512)
#define STB_(j, toff, bufB) { \
    const int _j = (j); \
    const unsigned short* _s = gbL + (size_t)(_j >= 36 ? 0 : _j) * 6144 + (toff); \
    unsigned short* _d = (_j >= 36) ? (ldsl + 69632) : ((bufB) + _j * 512); \
    gld_lds16(_s, _d); }

#define LDA_(buf) { \
    const unsigned short* _a = rdA + (buf) * 16384; \
    aF[0][0] = *(const short8*)(_a + rsw0);        aF[0][1] = *(const short8*)(_a + rsw1); \
    aF[1][0] = *(const short8*)(_a + 1024 + rsw0); aF[1][1] = *(const short8*)(_a + 1024 + rsw1); \
    aF[2][0] = *(const short8*)(_a + 2048 + rsw0); aF[2][1] = *(const short8*)(_a + 2048 + rsw1); \
    aF[3][0] = *(const short8*)(_a + 3072 + rsw0); aF[3][1] = *(const short8*)(_a + 3072 + rsw1); }

#define LDB_(buf, nh) { \
    const unsigned short* _b = rdB + (buf) * 18432 + (nh) * 3072; \
    bF[0][0] = *(const short8*)(_b + rsw0);        bF[0][1] = *(const short8*)(_b + rsw1); \
    bF[1][0] = *(const short8*)(_b + 1024 + rsw0); bF[1][1] = *(const short8*)(_b + 1024 + rsw1); \
    bF[2][0] = *(const short8*)(_b + 2048 + rsw0); bF[2][1] = *(const short8*)(_b + 2048 + rsw1); }

#define MMA_(nh) \
    __builtin_amdgcn_s_setprio(1); \
    _Pragma("unroll") for (int mt = 0; mt < 4; ++mt) \
    _Pragma("unroll") for (int nt = 0; nt < 3; ++nt) { \
        acc[mt][(nh) * 3 + nt] = __builtin_amdgcn_mfma_f32_16x16x32_bf16( \
            aF[mt][0], bF[nt][0], acc[mt][(nh) * 3 + nt], 0, 0, 0); \
        acc[mt][(nh) * 3 + nt] = __builtin_amdgcn_mfma_f32_16x16x32_bf16( \
            aF[mt][1], bF[nt][1], acc[mt][(nh) * 3 + nt], 0, 0, 0); } \
    __builtin_amdgcn_s_setprio(0);

#define BARRIER_ __builtin_amdgcn_s_barrier()
#define WLGKM0_ { asm volatile("s_waitcnt lgkmcnt(0)" ::: "memory"); __builtin_amdgcn_sched_barrier(0); }
#define WVM3_ asm volatile("s_waitcnt vmcnt(3)" ::: "memory")
#define WVM0_ asm volatile("s_waitcnt vmcnt(0)" ::: "memory")

    // ---- prologue: stage tile 0 (A first, then nh-sorted B; dummies last) ----
    {
        unsigned short* bufA = ldsl;            // buf0 A
        unsigned short* bufB = ldsl + 32768;    // buf0 B
        STA_(w, 0, bufA); STA_(w + 8, 0, bufA); STA_(w + 16, 0, bufA); STA_(w + 24, 0, bufA);
        STB_(b0, 0, bufB); STB_(b1, 0, bufB); STB_(b2, 0, bufB); STB_(b3, 0, bufB); STB_(b4, 0, bufB);
    }
    WVM3_; BARRIER_;

#pragma unroll 1
    for (int t = 0; t < NT - 1; ++t) {
        const int buf = t & 1;
        const int toff = (t + 1) * 64;
        unsigned short* bufA = ldsl + (buf ^ 1) * 16384;
        unsigned short* bufB = ldsl + 32768 + (buf ^ 1) * 18432;

        // phase 0 (nh=0)
        LDA_(buf); LDB_(buf, 0);
        STA_(w, toff, bufA); STA_(w + 8, toff, bufA); STA_(w + 16, toff, bufA);
        BARRIER_; WLGKM0_; MMA_(0);
        WVM3_; BARRIER_;
        // phase 1 (nh=1)
        LDB_(buf, 1);
        STA_(w + 24, toff, bufA); STB_(b0, toff, bufB); STB_(b1, toff, bufB);
        BARRIER_; WLGKM0_; MMA_(1);
        WVM3_; BARRIER_;
        // phase 2 (nh=2)
        LDB_(buf, 2);
        STB_(b2, toff, bufB); STB_(b3, toff, bufB); STB_(b4, toff, bufB);
        BARRIER_; WLGKM0_; MMA_(2);
        WVM3_; BARRIER_;
    }
    // ---- peeled last tile (t = NT-1 = 11, buf = 1): no stages ----
    {
        LDA_(1); LDB_(1, 0);
        BARRIER_; WLGKM0_; MMA_(0);
        WVM0_; BARRIER_;          // drain phase2(NT-2) stages before nh1/nh2 reads
        LDB_(1, 1);
        BARRIER_; WLGKM0_; MMA_(1);
        BARRIER_;
        LDB_(1, 2);
        BARRIER_; WLGKM0_; MMA_(2);
    }
#undef STA_
#undef STB_
#undef LDA_
#undef LDB_
#undef MMA_

    // ---- epilogue ----
    // row = bm + wM*64 + mt*16 + quad*4 + i ; col = bn + wN*144 + ntg*16 + l16
    const int bb = bm >> 10;
    const int tloc = (bm & 1023) + wM * 64;
#pragma unroll
    for (int ntg = 0; ntg < 9; ++ntg) {
        const int col = bn + wN * 144 + ntg * 16 + l16;
        const float bv = bias[col];
        if (col >= 1536) {
            // V -> Vt[(b*12+h)*64 + d][1024], transposed
            const int n = col - 1536;
            const int h = n >> 6, d = n & 63;
            const size_t vrow = (size_t)((bb * H_ + h) * 64 + d) * T_;
#pragma unroll
            for (int mt = 0; mt < 4; ++mt) {
                ushort4_ pk;
                pk.x = f2bf(acc[mt][ntg][0] + bv);
                pk.y = f2bf(acc[mt][ntg][1] + bv);
                pk.z = f2bf(acc[mt][ntg][2] + bv);
                pk.w = f2bf(acc[mt][ntg][3] + bv);
                *(ushort4_*)(Vt + vrow + tloc + mt * 16 + quad * 4) = pk;
            }
        } else {
            const float qs = (col < 768) ? SCALE_LOG2E : 1.0f;
#pragma unroll
            for (int mt = 0; mt < 4; ++mt) {
#pragma unroll
                for (int i = 0; i < 4; ++i) {
                    const int row = bm + wM * 64 + mt * 16 + quad * 4 + i;
                    mixedOut[(size_t)row * E3_ + col] = f2bf((acc[mt][ntg][i] + bv) * qs);
                }
            }
        }
    }
}

// ---------------------------------------------------------------------------
// MFMA flash attention (unchanged this round).
// ---------------------------------------------------------------------------
__global__ __launch_bounds__(256) void attn_mfma(const unsigned short* __restrict__ mixed,
                                                 const unsigned short* __restrict__ Vt,
                                                 unsigned short* __restrict__ ctx) {
    const int bh = blockIdx.x;
    const int b = bh / H_;
    const int h = bh % H_;
    const int q0 = blockIdx.y * 128;
    const int tid = threadIdx.x;
    const int lane = tid & 63;
    const int w = tid >> 6;
    const int quad = lane >> 4;
    const int l16 = lane & 15;

    __shared__ __align__(16) unsigned short Kl[8 * 520];
    __shared__ __align__(16) unsigned short Vl[8 * 520];
    __shared__ __align__(16) unsigned short Pl[4][32 * 72];
    unsigned short* pw = &Pl[w][0];

    short8 qf[2][2];
#pragma unroll
    for (int hh = 0; hh < 2; ++hh) {
        const size_t qrow = (size_t)(b * T_ + q0 + w * 32 + hh * 16 + l16) * E3_ + h * 64;
        qf[hh][0] = *(const short8*)(mixed + qrow + quad * 8);
        qf[hh][1] = *(const short8*)(mixed + qrow + 32 + quad * 8);
    }

    float4_ o[2][4] = {};
    float lps[2] = {0.0f, 0.0f};

    const size_t kbase = (size_t)(b * T_) * E3_ + E_ + h * 64;
    const size_t vtb = (size_t)bh * 64 * T_;

    const int srow = tid >> 3;
    const int sc = tid & 7;

    for (int kv0 = 0; kv0 < T_; kv0 += 64) {
        short8 k1 = *(const short8*)(mixed + kbase + (size_t)(kv0 + srow) * E3_ + sc * 8);
        short8 k2 = *(const short8*)(mixed + kbase + (size_t)(kv0 + srow + 32) * E3_ + sc * 8);
        short8 v1 = *(const short8*)(Vt + vtb + (size_t)srow * T_ + kv0 + sc * 8);
        short8 v2 = *(const short8*)(Vt + vtb + (size_t)(srow + 32) * T_ + kv0 + sc * 8);
        __syncthreads();
        *(short8*)(&Kl[sc * 520 + srow * 8]) = k1;
        *(short8*)(&Kl[sc * 520 + (srow + 32) * 8]) = k2;
        *(short8*)(&Vl[sc * 520 + srow * 8]) = v1;
        *(short8*)(&Vl[sc * 520 + (srow + 32) * 8]) = v2;
        __syncthreads();

        float4_ st[2][4];
#pragma unroll
        for (int nt = 0; nt < 4; ++nt) {
            const int key = nt * 16 + l16;
            short8 kf0 = *(const short8*)(&Kl[quad * 520 + key * 8]);
            short8 kf1 = *(const short8*)(&Kl[(4 + quad) * 520 + key * 8]);
#pragma unroll
            for (int hh = 0; hh < 2; ++hh) {
                float4_ z = {};
                z = __builtin_amdgcn_mfma_f32_16x16x32_bf16(kf0, qf[hh][0], z, 0, 0, 0);
                st[hh][nt] = __builtin_amdgcn_mfma_f32_16x16x32_bf16(kf1, qf[hh][1], z, 0, 0, 0);
            }
        }

#pragma unroll
        for (int hh = 0; hh < 2; ++hh) {
#pragma unroll
            for (int nt = 0; nt < 4; ++nt) {
                ushort4_ pk;
                float p0 = exp2f(st[hh][nt][0]);
                float p1 = exp2f(st[hh][nt][1]);
                float p2 = exp2f(st[hh][nt][2]);
                float p3 = exp2f(st[hh][nt][3]);
                pk.x = f2bf(p0); pk.y = f2bf(p1); pk.z = f2bf(p2); pk.w = f2bf(p3);
                lps[hh] += (p0 + p1) + (p2 + p3);
                *(ushort4_*)(&pw[(hh * 16 + l16) * 72 + nt * 16 + quad * 4]) = pk;
            }
        }

        short8 pf[2][2];
#pragma unroll
        for (int hh = 0; hh < 2; ++hh) {
            pf[hh][0] = *(const short8*)(&pw[(hh * 16 + l16) * 72 + quad * 8]);
            pf[hh][1] = *(const short8*)(&pw[(hh * 16 + l16) * 72 + 32 + quad * 8]);
        }

#pragma unroll
        for (int dt = 0; dt < 4; ++dt) {
            const int d = dt * 16 + l16;
            short8 vf0 = *(const short8*)(&Vl[quad * 520 + d * 8]);
            short8 vf1 = *(const short8*)(&Vl[(4 + quad) * 520 + d * 8]);
#pragma unroll
            for (int hh = 0; hh < 2; ++hh) {
                o[hh][dt] = __builtin_amdgcn_mfma_f32_16x16x32_bf16(pf[hh][0], vf0, o[hh][dt], 0, 0, 0);
                o[hh][dt] = __builtin_amdgcn_mfma_f32_16x16x32_bf16(pf[hh][1], vf1, o[hh][dt], 0, 0, 0);
            }
        }
    }

#pragma unroll
    for (int hh = 0; hh < 2; ++hh) {
        float l = lps[hh];
        l += __shfl_xor(l, 16, 64);
        l += __shfl_xor(l, 32, 64);
        float4_ inv;
#pragma unroll
        for (int i = 0; i < 4; ++i)
            inv[i] = 1.0f / __shfl(l, quad * 4 + i, 16);
#pragma unroll
        for (int dt = 0; dt < 4; ++dt) {
#pragma unroll
            for (int i = 0; i < 4; ++i) {
                const float v = o[hh][dt][i] * inv[i];
                const size_t row = (size_t)(b * T_ + q0 + w * 32 + hh * 16 + quad * 4 + i);
                ctx[row * E_ + h * 64 + dt * 16 + l16] = f2bf(v);
            }
        }
    }
}

// ---------------------------------------------------------------------------
extern "C" void kernel_launch(void* const* d_in, const int* in_sizes, int n_in,
                              void* d_out, int out_size, void* d_ws, size_t ws_size,
                              hipStream_t stream) {
    const float* hs     = (const float*)d_in[0];
    const float* qkv_w  = (const float*)d_in[1];
    const float* qkv_b  = (const float*)d_in[2];
    const float* proj_w = (const float*)d_in[3];
    const float* proj_b = (const float*)d_in[4];
    float* out = (float*)d_out;

    unsigned short* hs_bf  = (unsigned short*)d_ws;                 // [8192][768]
    unsigned short* qkvwT  = hs_bf + (size_t)M_ * E_;               // [2304][768]
    unsigned short* projwT = qkvwT + (size_t)E3_ * E_;              // [768][768]
    unsigned short* mixed  = projwT + (size_t)E_ * E_;              // [8192][2304]
    unsigned short* Vt     = mixed + (size_t)M_ * E3_;              // [96*64][1024]
    unsigned short* ctx    = hs_bf;  // alias: hs_bf dead after GEMM1

    // 0) fused prepasses: cast + both weight transposes
    prep<<<8448, 256, 0, stream>>>(hs, qkv_w, proj_w, hs_bf, qkvwT, projwT);

    // 1) QKV projection -> mixed (Q scaled, K bf16) + Vt (V transposed)
    //    NEW: 256x288 tile, 3-phase counted-vmcnt schedule, 256 blocks x 512
    gemm288<<<256, 512, 0, stream>>>(hs_bf, qkvwT, qkv_b, mixed, Vt);
    // 2) attention -> ctx (bf16)
    attn_mfma<<<dim3(B_ * H_, T_ / 128), 256, 0, stream>>>(mixed, Vt, ctx);
    // 3) output projection -> out (fp32), old 128x128 structure
    gemm_mfma<0><<<(E_ / 128) * (M_ / 128), 256, 0, stream>>>(ctx, projwT, proj_b,
                                                              (void*)out, nullptr, M_, E_, E_);
}

// Round 3
// 177.866 us; speedup vs baseline: 1.2077x; 1.0784x over previous
//
#include <hip/hip_runtime.h>
#include <hip/hip_bf16.h>

// Problem constants
#define B_ 8
#define T_ 1024
#define E_ 768
#define H_ 12
#define DH_ 64
#define E3_ 2304
#define M_ (B_ * T_)           // 8192 rows
// SCALE * log2(e): p = exp2(s * 0.125 * 1.4426950408889634)
// Applied to Q in gemm288's epilogue, NOT in the attention kernel.
#define SCALE_LOG2E 0.18033688011112042f

typedef __attribute__((ext_vector_type(8))) short short8;
typedef __attribute__((ext_vector_type(4))) float float4_;
typedef __attribute__((ext_vector_type(4))) unsigned short ushort4_;

__device__ __forceinline__ unsigned short f2bf(float f) {
    union { float f; unsigned int u; } v; v.f = f;
    unsigned int r = v.u + 0x7fffu + ((v.u >> 16) & 1u);
    return (unsigned short)(r >> 16);
}

// packed f32x2 -> bf16x2 (v_cvt_pk_bf16_f32, RNE — bit-identical to f2bf)
__device__ __forceinline__ unsigned int pk_bf16(float a, float b) {
    float2 t; t.x = a; t.y = b;
    union { __hip_bfloat162 h; unsigned int u; } cv;
    cv.h = __float22bfloat162_rn(t);
    return cv.u;
}

// async global->LDS, 16B per lane. LDS dest must be wave-uniform base + lane*16.
__device__ __forceinline__ void gld_lds16(const unsigned short* g, unsigned short* l) {
    __builtin_amdgcn_global_load_lds(
        (const __attribute__((address_space(1))) void*)g,
        (__attribute__((address_space(3))) void*)l,
        16, 0, 0);
}

// ---------------------------------------------------------------------------
// prep: one kernel for all prepasses (unchanged).
// ---------------------------------------------------------------------------
__global__ __launch_bounds__(256) void prep(const float* __restrict__ hs,
                                            const float* __restrict__ qkv_w,
                                            const float* __restrict__ proj_w,
                                            unsigned short* __restrict__ hs_bf,
                                            unsigned short* __restrict__ qkvwT,
                                            unsigned short* __restrict__ projwT) {
    __shared__ float tile[32][33];
    const int id = blockIdx.x;
    const int tid = threadIdx.x;
    if (id < 6144) {
        const int i = (id * 256 + tid) * 4;
        float4_ v = *(const float4_*)(hs + i);
        ushort4_ o;
        o.x = f2bf(v.x); o.y = f2bf(v.y); o.z = f2bf(v.z); o.w = f2bf(v.w);
        *(ushort4_*)(hs_bf + i) = o;
        return;
    }
    const float* W; unsigned short* Wt; int N, bx, by;
    if (id < 6144 + 1728) {
        const int t = id - 6144; W = qkv_w; Wt = qkvwT; N = E3_;
        bx = t % 72; by = t / 72;
    } else {
        const int t = id - 7872; W = proj_w; Wt = projwT; N = E_;
        bx = t % 24; by = t / 24;
    }
    const int k0 = by * 32, n0 = bx * 32;
    const int tx = tid & 31, ty = tid >> 5;
    for (int i = ty; i < 32; i += 8)
        tile[i][tx] = W[(size_t)(k0 + i) * N + n0 + tx];
    __syncthreads();
    for (int i = ty; i < 32; i += 8)
        Wt[(size_t)(n0 + i) * E_ + k0 + tx] = f2bf(tile[tx][i]);
}

// ---------------------------------------------------------------------------
// OLD 128x128 2-phase GEMM: kept for the output projection (N=768; 384 blocks
// at 2 blocks/CU co-resident).
// ---------------------------------------------------------------------------
template <int STORE_MODE>
__global__ __launch_bounds__(256) void gemm_mfma(const unsigned short* __restrict__ A,
                                                 const unsigned short* __restrict__ Wt,
                                                 const float* __restrict__ bias,
                                                 void* __restrict__ Cout,
                                                 unsigned short* __restrict__ Vt,
                                                 int M, int N, int K) {
    __shared__ __align__(16) unsigned short Al[2][128 * 32];
    __shared__ __align__(16) unsigned short Wl[2][128 * 32];

    const int tid = threadIdx.x;
    const int lane = tid & 63;
    const int w = tid >> 6;

    const int id = blockIdx.x;
    const int xcd = id & 7;
    const int slot = id >> 3;
    const int bx = slot >> 3;
    const int by = xcd * 8 + (slot & 7);
    const int bm = by * 128;
    const int bn = bx * 128;

    const int wm = (w >> 1) * 64;
    const int wn = (w & 1) * 64;
    const int quad = lane >> 4;
    const int l16 = lane & 15;

    const int srow = w * 32 + (lane >> 2);
    const int schunk = (lane & 3) * 8;
    const int sbase = w * 32 * 32 + lane * 8;

    const unsigned short* ga = A + (size_t)(bm + srow) * K + schunk;
    const unsigned short* gw = Wt + (size_t)(bn + srow) * K + schunk;

    float4_ acc[4][4] = {};

    gld_lds16(ga, &Al[0][sbase]);
    gld_lds16(ga + (size_t)16 * K, &Al[0][sbase + 512]);
    gld_lds16(gw, &Wl[0][sbase]);
    gld_lds16(gw + (size_t)16 * K, &Wl[0][sbase + 512]);

    const int NI = K >> 5;
    for (int i = 0; i < NI; ++i) {
        const int cur = i & 1;
        __syncthreads();
        if (i + 1 < NI) {
            const unsigned short* ga2 = ga + (size_t)(i + 1) * 32;
            const unsigned short* gw2 = gw + (size_t)(i + 1) * 32;
            const int nxt = cur ^ 1;
            gld_lds16(ga2, &Al[nxt][sbase]);
            gld_lds16(ga2 + (size_t)16 * K, &Al[nxt][sbase + 512]);
            gld_lds16(gw2, &Wl[nxt][sbase]);
            gld_lds16(gw2 + (size_t)16 * K, &Wl[nxt][sbase + 512]);
        }
        short8 af[4], bf[4];
#pragma unroll
        for (int mt = 0; mt < 4; ++mt)
            af[mt] = *(const short8*)(&Al[cur][(wm + mt * 16 + l16) * 32 + quad * 8]);
#pragma unroll
        for (int nt = 0; nt < 4; ++nt)
            bf[nt] = *(const short8*)(&Wl[cur][(wn + nt * 16 + l16) * 32 + quad * 8]);
#pragma unroll
        for (int mt = 0; mt < 4; ++mt)
#pragma unroll
            for (int nt = 0; nt < 4; ++nt)
                acc[mt][nt] = __builtin_amdgcn_mfma_f32_16x16x32_bf16(af[mt], bf[nt],
                                                                      acc[mt][nt], 0, 0, 0);
    }

    {
#pragma unroll
        for (int nt = 0; nt < 4; ++nt) {
            const int col = bn + wn + nt * 16 + l16;
            const float bv = bias[col];
#pragma unroll
            for (int mt = 0; mt < 4; ++mt) {
#pragma unroll
                for (int i = 0; i < 4; ++i) {
                    const int row = bm + wm + mt * 16 + quad * 4 + i;
                    const float v = acc[mt][nt][i] + bv;
                    if (STORE_MODE >= 1)
                        ((unsigned short*)Cout)[(size_t)row * N + col] = f2bf(v);
                    else
                        ((float*)Cout)[(size_t)row * N + col] = v;
                }
            }
        }
    }
    (void)Vt;
}

// ---------------------------------------------------------------------------
// 256x288 3-phase GEMM for the QKV projection (R2 structure, unchanged except
// packed bf16 conversion in the V epilogue). Grid = 256 blocks = 1/CU.
// ---------------------------------------------------------------------------
__global__ __launch_bounds__(512, 2) void gemm288(const unsigned short* __restrict__ A,
                                                  const unsigned short* __restrict__ Wt,
                                                  const float* __restrict__ bias,
                                                  unsigned short* __restrict__ mixedOut,
                                                  unsigned short* __restrict__ Vt) {
    const int K = 768;
    const int NT = 12;                 // K / 64
    __shared__ __align__(16) unsigned short lds[70144]; // A:2*16384 | B:2*18432 | scratch:512

    const int tid = threadIdx.x;
    const int lane = tid & 63;
    const int w = tid >> 6;            // 0..7
    const int quad = lane >> 4;
    const int l16 = lane & 15;
    const int wM = w >> 1;             // 0..3 (64-row slice)
    const int wN = w & 1;              // 0..1 (144-col slice)

    // grid 256 = 8 xcd * (8 bx * 4 byl), byl innermost
    const int id = blockIdx.x;
    const int xcd = id & 7;
    const int slot = id >> 3;          // 0..31
    const int bx = slot >> 2;          // 0..7
    const int byl = slot & 3;
    const int bm = (xcd * 4 + byl) * 256;
    const int bn = bx * 288;

    // ---- B granule ownership, sorted by nh third (wave-uniform) ----
    const int j4 = (w < 4) ? (w + 32) : 36;
    int kk0 = ((w % 18) / 6) * 64 + w;
    int kk1 = (((w + 8) % 18) / 6) * 64 + (w + 8);
    int kk2 = (((w + 16) % 18) / 6) * 64 + (w + 16);
    int kk3 = (((w + 24) % 18) / 6) * 64 + (w + 24);
    int kk4 = (j4 >= 36) ? (3 * 64 + 36) : (((j4 % 18) / 6) * 64 + j4);
#define CS_(a, b) { int _lo = min(a, b), _hi = max(a, b); a = _lo; b = _hi; }
    CS_(kk0, kk1) CS_(kk3, kk4) CS_(kk2, kk4) CS_(kk2, kk3) CS_(kk1, kk4)
    CS_(kk0, kk3) CS_(kk0, kk2) CS_(kk1, kk3) CS_(kk1, kk2)
#undef CS_
    const int b0 = kk0 & 63, b1 = kk1 & 63, b2 = kk2 & 63, b3 = kk3 & 63, b4 = kk4 & 63;

    // ---- staging constants ----
    const int srcrow = lane >> 3;                               // row within granule
    const int ssw = ((lane & 7) ^ (srcrow & 7)) << 3;           // swizzled src chunk (elems)
    const unsigned short* gaL = A + (size_t)(bm + srcrow) * K + ssw;
    const unsigned short* gbL = Wt + (size_t)(bn + srcrow) * K + ssw;
    unsigned short* ldsl = lds + lane * 8;

    // ---- fragment-read constants ----
    const int rsw0 = ((quad) ^ (l16 & 7)) << 3;                 // ks=0
    const int rsw1 = ((quad + 4) ^ (l16 & 7)) << 3;             // ks=1
    const unsigned short* rdA = lds + (wM * 64 + l16) * 64;
    const unsigned short* rdB = lds + 32768 + (wN * 144 + l16) * 64;

    short8 aF[4][2], bF[3][2];
    float4_ acc[4][9] = {};

#define STA_(aj, toff, bufA) gld_lds16(gaL + (size_t)(aj) * 6144 + (toff), (bufA) + (aj) * 512)
#define STB_(j, toff, bufB) { \
    const int _j = (j); \
    const unsigned short* _s = gbL + (size_t)(_j >= 36 ? 0 : _j) * 6144 + (toff); \
    unsigned short* _d = (_j >= 36) ? (ldsl + 69632) : ((bufB) + _j * 512); \
    gld_lds16(_s, _d); }

#define LDA_(buf) { \
    const unsigned short* _a = rdA + (buf) * 16384; \
    aF[0][0] = *(const short8*)(_a + rsw0);        aF[0][1] = *(const short8*)(_a + rsw1); \
    aF[1][0] = *(const short8*)(_a + 1024 + rsw0); aF[1][1] = *(const short8*)(_a + 1024 + rsw1); \
    aF[2][0] = *(const short8*)(_a + 2048 + rsw0); aF[2][1] = *(const short8*)(_a + 2048 + rsw1); \
    aF[3][0] = *(const short8*)(_a + 3072 + rsw0); aF[3][1] = *(const short8*)(_a + 3072 + rsw1); }

#define LDB_(buf, nh) { \
    const unsigned short* _b = rdB + (buf) * 18432 + (nh) * 3072; \
    bF[0][0] = *(const short8*)(_b + rsw0);        bF[0][1] = *(const short8*)(_b + rsw1); \
    bF[1][0] = *(const short8*)(_b + 1024 + rsw0); bF[1][1] = *(const short8*)(_b + 1024 + rsw1); \
    bF[2][0] = *(const short8*)(_b + 2048 + rsw0); bF[2][1] = *(const short8*)(_b + 2048 + rsw1); }

#define MMA_(nh) \
    __builtin_amdgcn_s_setprio(1); \
    _Pragma("unroll") for (int mt = 0; mt < 4; ++mt) \
    _Pragma("unroll") for (int nt = 0; nt < 3; ++nt) { \
        acc[mt][(nh) * 3 + nt] = __builtin_amdgcn_mfma_f32_16x16x32_bf16( \
            aF[mt][0], bF[nt][0], acc[mt][(nh) * 3 + nt], 0, 0, 0); \
        acc[mt][(nh) * 3 + nt] = __builtin_amdgcn_mfma_f32_16x16x32_bf16( \
            aF[mt][1], bF[nt][1], acc[mt][(nh) * 3 + nt], 0, 0, 0); } \
    __builtin_amdgcn_s_setprio(0);

#define BARRIER_ __builtin_amdgcn_s_barrier()
#define WLGKM0_ { asm volatile("s_waitcnt lgkmcnt(0)" ::: "memory"); __builtin_amdgcn_sched_barrier(0); }
#define WVM3_ asm volatile("s_waitcnt vmcnt(3)" ::: "memory")
#define WVM0_ asm volatile("s_waitcnt vmcnt(0)" ::: "memory")

    // ---- prologue: stage tile 0 (A first, then nh-sorted B; dummies last) ----
    {
        unsigned short* bufA = ldsl;            // buf0 A
        unsigned short* bufB = ldsl + 32768;    // buf0 B
        STA_(w, 0, bufA); STA_(w + 8, 0, bufA); STA_(w + 16, 0, bufA); STA_(w + 24, 0, bufA);
        STB_(b0, 0, bufB); STB_(b1, 0, bufB); STB_(b2, 0, bufB); STB_(b3, 0, bufB); STB_(b4, 0, bufB);
    }
    WVM3_; BARRIER_;

#pragma unroll 1
    for (int t = 0; t < NT - 1; ++t) {
        const int buf = t & 1;
        const int toff = (t + 1) * 64;
        unsigned short* bufA = ldsl + (buf ^ 1) * 16384;
        unsigned short* bufB = ldsl + 32768 + (buf ^ 1) * 18432;

        // phase 0 (nh=0)
        LDA_(buf); LDB_(buf, 0);
        STA_(w, toff, bufA); STA_(w + 8, toff, bufA); STA_(w + 16, toff, bufA);
        BARRIER_; WLGKM0_; MMA_(0);
        WVM3_; BARRIER_;
        // phase 1 (nh=1)
        LDB_(buf, 1);
        STA_(w + 24, toff, bufA); STB_(b0, toff, bufB); STB_(b1, toff, bufB);
        BARRIER_; WLGKM0_; MMA_(1);
        WVM3_; BARRIER_;
        // phase 2 (nh=2)
        LDB_(buf, 2);
        STB_(b2, toff, bufB); STB_(b3, toff, bufB); STB_(b4, toff, bufB);
        BARRIER_; WLGKM0_; MMA_(2);
        WVM3_; BARRIER_;
    }
    // ---- peeled last tile (t = NT-1 = 11, buf = 1): no stages ----
    {
        LDA_(1); LDB_(1, 0);
        BARRIER_; WLGKM0_; MMA_(0);
        WVM0_; BARRIER_;          // drain phase2(NT-2) stages before nh1/nh2 reads
        LDB_(1, 1);
        BARRIER_; WLGKM0_; MMA_(1);
        BARRIER_;
        LDB_(1, 2);
        BARRIER_; WLGKM0_; MMA_(2);
    }
#undef STA_
#undef STB_
#undef LDA_
#undef LDB_
#undef MMA_

    // ---- epilogue ----
    // row = bm + wM*64 + mt*16 + quad*4 + i ; col = bn + wN*144 + ntg*16 + l16
    const int bb = bm >> 10;
    const int tloc = (bm & 1023) + wM * 64;
#pragma unroll
    for (int ntg = 0; ntg < 9; ++ntg) {
        const int col = bn + wN * 144 + ntg * 16 + l16;
        const float bv = bias[col];
        if (col >= 1536) {
            // V -> Vt[(b*12+h)*64 + d][1024], transposed
            const int n = col - 1536;
            const int h = n >> 6, d = n & 63;
            const size_t vrow = (size_t)((bb * H_ + h) * 64 + d) * T_;
#pragma unroll
            for (int mt = 0; mt < 4; ++mt) {
                uint2 pk;
                pk.x = pk_bf16(acc[mt][ntg][0] + bv, acc[mt][ntg][1] + bv);
                pk.y = pk_bf16(acc[mt][ntg][2] + bv, acc[mt][ntg][3] + bv);
                *(uint2*)(Vt + vrow + tloc + mt * 16 + quad * 4) = pk;
            }
        } else {
            const float qs = (col < 768) ? SCALE_LOG2E : 1.0f;
#pragma unroll
            for (int mt = 0; mt < 4; ++mt) {
#pragma unroll
                for (int i = 0; i < 4; ++i) {
                    const int row = bm + wM * 64 + mt * 16 + quad * 4 + i;
                    mixedOut[(size_t)row * E3_ + col] = f2bf((acc[mt][ntg][i] + bv) * qs);
                }
            }
        }
    }
}

// ---------------------------------------------------------------------------
// MFMA flash attention. R3 change: VALU diet in the softmax path.
//   - exp2f -> __builtin_amdgcn_exp2f (bare v_exp_f32; inputs are small
//     finite scores, no denorm fixup needed)
//   - manual f2bf pair -> v_cvt_pk_bf16_f32 via __float22bfloat162_rn
//     (RNE, bit-identical to f2bf)
// Counters said VALUBusy 59% vs MfmaUtil 17%: softmax conversion scalar ops
// were ~4x the MFMA work. Structure/layout unchanged.
// ---------------------------------------------------------------------------
__global__ __launch_bounds__(256) void attn_mfma(const unsigned short* __restrict__ mixed,
                                                 const unsigned short* __restrict__ Vt,
                                                 unsigned short* __restrict__ ctx) {
    const int bh = blockIdx.x;
    const int b = bh / H_;
    const int h = bh % H_;
    const int q0 = blockIdx.y * 128;
    const int tid = threadIdx.x;
    const int lane = tid & 63;
    const int w = tid >> 6;
    const int quad = lane >> 4;
    const int l16 = lane & 15;

    __shared__ __align__(16) unsigned short Kl[8 * 520];
    __shared__ __align__(16) unsigned short Vl[8 * 520];
    __shared__ __align__(16) unsigned short Pl[4][32 * 72];
    unsigned short* pw = &Pl[w][0];

    short8 qf[2][2];
#pragma unroll
    for (int hh = 0; hh < 2; ++hh) {
        const size_t qrow = (size_t)(b * T_ + q0 + w * 32 + hh * 16 + l16) * E3_ + h * 64;
        qf[hh][0] = *(const short8*)(mixed + qrow + quad * 8);
        qf[hh][1] = *(const short8*)(mixed + qrow + 32 + quad * 8);
    }

    float4_ o[2][4] = {};
    float lps[2] = {0.0f, 0.0f};

    const size_t kbase = (size_t)(b * T_) * E3_ + E_ + h * 64;
    const size_t vtb = (size_t)bh * 64 * T_;

    const int srow = tid >> 3;
    const int sc = tid & 7;

    for (int kv0 = 0; kv0 < T_; kv0 += 64) {
        short8 k1 = *(const short8*)(mixed + kbase + (size_t)(kv0 + srow) * E3_ + sc * 8);
        short8 k2 = *(const short8*)(mixed + kbase + (size_t)(kv0 + srow + 32) * E3_ + sc * 8);
        short8 v1 = *(const short8*)(Vt + vtb + (size_t)srow * T_ + kv0 + sc * 8);
        short8 v2 = *(const short8*)(Vt + vtb + (size_t)(srow + 32) * T_ + kv0 + sc * 8);
        __syncthreads();
        *(short8*)(&Kl[sc * 520 + srow * 8]) = k1;
        *(short8*)(&Kl[sc * 520 + (srow + 32) * 8]) = k2;
        *(short8*)(&Vl[sc * 520 + srow * 8]) = v1;
        *(short8*)(&Vl[sc * 520 + (srow + 32) * 8]) = v2;
        __syncthreads();

        float4_ st[2][4];
#pragma unroll
        for (int nt = 0; nt < 4; ++nt) {
            const int key = nt * 16 + l16;
            short8 kf0 = *(const short8*)(&Kl[quad * 520 + key * 8]);
            short8 kf1 = *(const short8*)(&Kl[(4 + quad) * 520 + key * 8]);
#pragma unroll
            for (int hh = 0; hh < 2; ++hh) {
                float4_ z = {};
                z = __builtin_amdgcn_mfma_f32_16x16x32_bf16(kf0, qf[hh][0], z, 0, 0, 0);
                st[hh][nt] = __builtin_amdgcn_mfma_f32_16x16x32_bf16(kf1, qf[hh][1], z, 0, 0, 0);
            }
        }

#pragma unroll
        for (int hh = 0; hh < 2; ++hh) {
#pragma unroll
            for (int nt = 0; nt < 4; ++nt) {
                const float p0 = __builtin_amdgcn_exp2f(st[hh][nt][0]);
                const float p1 = __builtin_amdgcn_exp2f(st[hh][nt][1]);
                const float p2 = __builtin_amdgcn_exp2f(st[hh][nt][2]);
                const float p3 = __builtin_amdgcn_exp2f(st[hh][nt][3]);
                uint2 pk;
                pk.x = pk_bf16(p0, p1);
                pk.y = pk_bf16(p2, p3);
                lps[hh] += (p0 + p1) + (p2 + p3);
                *(uint2*)(&pw[(hh * 16 + l16) * 72 + nt * 16 + quad * 4]) = pk;
            }
        }

        short8 pf[2][2];
#pragma unroll
        for (int hh = 0; hh < 2; ++hh) {
            pf[hh][0] = *(const short8*)(&pw[(hh * 16 + l16) * 72 + quad * 8]);
            pf[hh][1] = *(const short8*)(&pw[(hh * 16 + l16) * 72 + 32 + quad * 8]);
        }

#pragma unroll
        for (int dt = 0; dt < 4; ++dt) {
            const int d = dt * 16 + l16;
            short8 vf0 = *(const short8*)(&Vl[quad * 520 + d * 8]);
            short8 vf1 = *(const short8*)(&Vl[(4 + quad) * 520 + d * 8]);
#pragma unroll
            for (int hh = 0; hh < 2; ++hh) {
                o[hh][dt] = __builtin_amdgcn_mfma_f32_16x16x32_bf16(pf[hh][0], vf0, o[hh][dt], 0, 0, 0);
                o[hh][dt] = __builtin_amdgcn_mfma_f32_16x16x32_bf16(pf[hh][1], vf1, o[hh][dt], 0, 0, 0);
            }
        }
    }

#pragma unroll
    for (int hh = 0; hh < 2; ++hh) {
        float l = lps[hh];
        l += __shfl_xor(l, 16, 64);
        l += __shfl_xor(l, 32, 64);
        float4_ inv;
#pragma unroll
        for (int i = 0; i < 4; ++i)
            inv[i] = 1.0f / __shfl(l, quad * 4 + i, 16);
#pragma unroll
        for (int dt = 0; dt < 4; ++dt) {
#pragma unroll
            for (int i = 0; i < 4; ++i) {
                const float v = o[hh][dt][i] * inv[i];
                const size_t row = (size_t)(b * T_ + q0 + w * 32 + hh * 16 + quad * 4 + i);
                ctx[row * E_ + h * 64 + dt * 16 + l16] = f2bf(v);
            }
        }
    }
}

// ---------------------------------------------------------------------------
extern "C" void kernel_launch(void* const* d_in, const int* in_sizes, int n_in,
                              void* d_out, int out_size, void* d_ws, size_t ws_size,
                              hipStream_t stream) {
    const float* hs     = (const float*)d_in[0];
    const float* qkv_w  = (const float*)d_in[1];
    const float* qkv_b  = (const float*)d_in[2];
    const float* proj_w = (const float*)d_in[3];
    const float* proj_b = (const float*)d_in[4];
    float* out = (float*)d_out;

    unsigned short* hs_bf  = (unsigned short*)d_ws;                 // [8192][768]
    unsigned short* qkvwT  = hs_bf + (size_t)M_ * E_;               // [2304][768]
    unsigned short* projwT = qkvwT + (size_t)E3_ * E_;              // [768][768]
    unsigned short* mixed  = projwT + (size_t)E_ * E_;              // [8192][2304]
    unsigned short* Vt     = mixed + (size_t)M_ * E3_;              // [96*64][1024]
    unsigned short* ctx    = hs_bf;  // alias: hs_bf dead after GEMM1

    // 0) fused prepasses: cast + both weight transposes
    prep<<<8448, 256, 0, stream>>>(hs, qkv_w, proj_w, hs_bf, qkvwT, projwT);

    // 1) QKV projection -> mixed (Q scaled, K bf16) + Vt (V transposed)
    gemm288<<<256, 512, 0, stream>>>(hs_bf, qkvwT, qkv_b, mixed, Vt);
    // 2) attention -> ctx (bf16)
    attn_mfma<<<dim3(B_ * H_, T_ / 128), 256, 0, stream>>>(mixed, Vt, ctx);
    // 3) output projection -> out (fp32), old 128x128 structure
    gemm_mfma<0><<<(E_ / 128) * (M_ / 128), 256, 0, stream>>>(ctx, projwT, proj_b,
                                                              (void*)out, nullptr, M_, E_, E_);
}